// Round 11
// baseline (207.980 us; speedup 1.0000x reference)
//
#include <hip/hip_runtime.h>

// GNN: 2 x (SimpleConv(mean, cat) -> Linear(256->128) -> ReLU)
// N=50000 nodes, E=640000 edges, H=128.
//
// R1-R14: CSR pipeline, bf16, MFMA gemm, 5 kernels + memset. 209.7us.
// R15-R18: slice-major [4][N][32] hidden state; quad-per-node gather; fill
//      XCD partition + upfront scan loads. 214.2.
// R19 ACCOUNTING: ~77us dispatch-serialization overhead. R20 FAILED
//      (cooperative launch vs graph capture). R21 REGRESSED 594 (persistent
//      grid pinned occupancy).
// R22: agg+gemm fused per 64-node block (serial 4 passes, LDS agg tile).
//      206.1. k_layer 45us @ 12 waves/CU, FETCH 63MB.
// R23 REGRESSED 225: NPB=16 all-slices-concurrent -> FETCH 2x. Locality>waves.
// R24 FAILED correctness: per-wave col-split covered 4/16 output tiles.
// R25: gemm coverage fixed; pass-PAIR agg; stage-flattened fill. 205.1.
//      k_layer STILL 45us: exposures 6.4->3.2 changed nothing. Occ 28% --
//      grid 782 = 3.05 blocks/CU is the cap. 79MB random misses at 1.8TB/s:
//      not exposure-bound, MISS-PARALLELISM bound.
// R26: NPB=32 -> grid 1563 = 6.1 blocks/CU (2x outstanding misses), keep
//      slice-SERIAL passes (R22 locality). All 4 waves active on agg via
//      edge-split: quad q takes batches {0-7,16-23}, quad q+8 takes
//      {8-15,24-31}; combine with one shfl_xor(32) per channel. LDS 13.3KB,
//      launch_bounds(256,6). Gemm: 2 row-bands x 2 col-halves (4 B-frags/
//      wave, full coverage). Fill unchanged from R25.

#define HDIM 128
#define CAP 32            // padded CSR slots/node; P(deg>32 | Poisson 12.8) ~ 2e-6
#define FCH 2048          // edges per fill chunk
#define NPB 32            // nodes per k_layer block

typedef __bf16 bf16x8 __attribute__((ext_vector_type(8)));
typedef float floatx4 __attribute__((ext_vector_type(4)));

__device__ __forceinline__ unsigned short f2bf(float f) {
    unsigned int u = __float_as_uint(f);
    unsigned int r = (u + 0x7fff + ((u >> 16) & 1)) >> 16;   // RNE
    return (unsigned short)r;
}
__device__ __forceinline__ float bf2f(unsigned short b) {
    return __uint_as_float((unsigned int)b << 16);
}
__device__ __forceinline__ void acc8(const uint4& u, float a, float* s) {
    s[0] = fmaf(bf2f((unsigned short)(u.x & 0xffff)), a, s[0]);
    s[1] = fmaf(bf2f((unsigned short)(u.x >> 16)), a, s[1]);
    s[2] = fmaf(bf2f((unsigned short)(u.y & 0xffff)), a, s[2]);
    s[3] = fmaf(bf2f((unsigned short)(u.y >> 16)), a, s[3]);
    s[4] = fmaf(bf2f((unsigned short)(u.z & 0xffff)), a, s[4]);
    s[5] = fmaf(bf2f((unsigned short)(u.z >> 16)), a, s[5]);
    s[6] = fmaf(bf2f((unsigned short)(u.w & 0xffff)), a, s[6]);
    s[7] = fmaf(bf2f((unsigned short)(u.w >> 16)), a, s[7]);
}

// Fused: XCD-partitioned padded-CSR fill | fp32->bf16 cast (slice-major
// [4][N][32]) | prepW (wave-coalesced Wsw). Fill: stage-flattened issue.
__global__ __launch_bounds__(256) void k_fill(const int* __restrict__ edge, int E,
                                              const float* __restrict__ att,
                                              int* __restrict__ cursor,
                                              int* __restrict__ ovf_cnt,
                                              unsigned int* __restrict__ pse,
                                              float4* __restrict__ ovf, int rsize,
                                              int nfb,
                                              const float* __restrict__ data,
                                              unsigned short* __restrict__ data_bf, int n4,
                                              int cb, int NN,
                                              const float* __restrict__ w1,
                                              unsigned short* __restrict__ w1s,
                                              const float* __restrict__ w2,
                                              unsigned short* __restrict__ w2s) {
    int b = blockIdx.x;
    int t = threadIdx.x;
    if (b < nfb) {
        __shared__ int s_or;
        if (t == 0) s_or = 0;
        __syncthreads();
        int nw = 2 * E < 512 ? 2 * E : 512;
        int iw = t * 2 + 1;
        int vw = (iw < nw) ? edge[iw] : 0;
        if (vw != 0) atomicOr(&s_or, 1);
        __syncthreads();
        int sh = (s_or == 0) ? 1 : 0;  // 1 => int64 stride, 0 => int32

        int r = b & 7;
        int c = b >> 3;
        int lo = r * rsize;
        int hi = lo + rsize;
        int e0 = c * FCH;
        // Stage 1: 8 dst scan loads (independent).
        int ds[8];
#pragma unroll
        for (int k = 0; k < 8; ++k) {
            int e = e0 + t + k * 256;
            ds[k] = (e < E) ? edge[(size_t)(E + e) << sh] : -1;
        }
        bool ir[8];
#pragma unroll
        for (int k = 0; k < 8; ++k) ir[k] = (ds[k] >= lo && ds[k] < hi);
        // Stage 2: predicated src+att loads (independent).
        int sv[8];
        float av[8];
#pragma unroll
        for (int k = 0; k < 8; ++k) {
            if (ir[k]) {
                int e = e0 + t + k * 256;
                sv[k] = edge[(size_t)e << sh];
                av[k] = att[e];
            }
        }
        // Stage 3: predicated slot atomics (independent).
        int sl[8];
#pragma unroll
        for (int k = 0; k < 8; ++k) {
            if (ir[k]) sl[k] = atomicAdd(&cursor[ds[k]], 1);
        }
        // Stage 4: predicated record stores.
#pragma unroll
        for (int k = 0; k < 8; ++k) {
            if (ir[k]) {
                if (sl[k] < CAP) {
                    unsigned int rec = ((unsigned int)f2bf(av[k]) << 16) | (unsigned int)(sv[k] & 0xffff);
                    pse[(size_t)ds[k] * CAP + sl[k]] = rec;
                } else {
                    int oi = atomicAdd(ovf_cnt, 1);
                    ovf[oi] = make_float4(__int_as_float(ds[k]), __int_as_float(sv[k]), av[k], 0.f);
                }
            }
        }
        return;
    }
    b -= nfb;
    if (b < cb) {
        int i = b * 256 + t;
        if (i < n4) {
            float4 v = ((const float4*)data)[i];
            ushort4 o;
            o.x = f2bf(v.x); o.y = f2bf(v.y); o.z = f2bf(v.z); o.w = f2bf(v.w);
            int nn = i >> 5;           // node
            int c4 = i & 31;           // which float4 of the row (ch 4*c4)
            // slice-major: [slice][N][32]
            *(ushort4*)(data_bf + (((size_t)(c4 >> 3) * NN + nn) << 5) + ((c4 & 7) << 2)) = o;
        }
        return;
    }
    b -= cb;
    {
        const float* w = (b < 128) ? w1 : w2;
        unsigned short* wt = (b < 128) ? w1s : w2s;
        int bb = (b < 128) ? b : b - 128;
        int idx = bb * 256 + t;          // 0..32767
        int k = idx >> 7;                // 0..255
        int n = idx & 127;               // 0..127
        // wave-coalesced: gemm reads Wsw[((c*8+kc)*64+lane)*8+j]  (R21-validated)
        int c = n >> 4, l16 = n & 15;
        int kc = k >> 5, quad = (k >> 3) & 3, j = k & 7;
        int lane = quad * 16 + l16;
        size_t f = (((size_t)(c * 8 + kc) * 64 + lane) << 3) + j;
        wt[f] = f2bf(w[(size_t)k * 128 + n]);
    }
}

// Fused layer, NPB=32. Agg: slice-SERIAL 4 passes (locality); per node, the
// edge list is split across wave halves: quad q (lane<32) takes batches
// {0-7,16-23}, quad q+8 takes {8-15,24-31}; combined with shfl_xor(32).
// All 4 waves active (wave w owns nodes w*8..w*8+7). Gemm: wave = (row band
// rb=w&1) x (col half ch=w>>1), 4 B-frags streamed from Wsw (L2). X A-frags
// prefetch before the barrier. x slice-major [4][M][32] bf16.
// outB (layer1) slice-major bf16; outF (layer2) row-major f32.
__global__ __launch_bounds__(256, 6) void k_layer(const unsigned short* __restrict__ x,
                                                  const unsigned int* __restrict__ pse,
                                                  const int* __restrict__ cursor,
                                                  const int* __restrict__ ovf_cnt,
                                                  const float4* __restrict__ ovf,
                                                  const unsigned short* __restrict__ Wsw,
                                                  const float* __restrict__ bias,
                                                  float* __restrict__ outF,
                                                  unsigned short* __restrict__ outB,
                                                  int M) {
    __shared__ __align__(16) unsigned int s_rec[NPB * 36];      // 4608 B
    __shared__ __align__(16) unsigned short s_agg[NPB * 136];   // 8704 B
    int tid = threadIdx.x;
    int base = blockIdx.x * NPB;

    // Stage 32 nodes x 32 records (256 uint4s, one per thread, coalesced).
    {
        int i = tid >> 3;                // node local 0..31
        int j0 = (tid & 7) << 2;         // slot 0,4,...,28
        int nn = base + i;
        uint4 v = make_uint4(0u, 0u, 0u, 0u);
        if (nn < M) v = *(const uint4*)(pse + ((size_t)nn << 5) + j0);
        *(uint4*)(&s_rec[i * 36 + j0]) = v;
    }
    __syncthreads();

    int lane = tid & 63;
    int wave = tid >> 6;
    int q = lane >> 2;            // quad 0..15
    int l4 = lane & 3;            // 16B sub-segment of the 64B slice row
    int hi = q >> 3;              // edge-list half (0: batches 0-7/16-23)
    int ni = wave * 8 + (q & 7);  // node local 0..31
    int n = base + ni;
    bool valid = n < M;
    int deg = valid ? cursor[n] : 0;
    int m = min(deg, CAP);
    const unsigned int* rp = &s_rec[ni * 36];
    float inv = 1.0f / fmaxf((float)deg, 1.0f);
    int oc = ovf_cnt[0];

    // ---- agg: serial passes; edge halves run on wave halves concurrently.
#pragma unroll
    for (int pass = 0; pass < 4; ++pass) {
        const unsigned short* xs = x + (((size_t)pass * M) << 5) + (l4 << 3);
        float s[8] = {0.f, 0.f, 0.f, 0.f, 0.f, 0.f, 0.f, 0.f};

        for (int j = hi * 8; j < m; j += 16) {
            unsigned int rr[8];
#pragma unroll
            for (int k = 0; k < 8; ++k) {
                unsigned int rv = rp[j + k];         // padded row (36), j+k<=31
                rr[k] = (j + k < m) ? rv : 0u;       // rec=0 -> row0, att=0
            }
            uint4 uu[8];
#pragma unroll
            for (int k = 0; k < 8; ++k)
                uu[k] = *(const uint4*)(xs + ((size_t)(rr[k] & 0xffffu) << 5));
#pragma unroll
            for (int k = 0; k < 8; ++k)
                acc8(uu[k], __uint_as_float(rr[k] & 0xffff0000u), s);
        }

        if (oc > 0 && valid && hi == 0) {   // overflow path, half 0 only
            for (int k = 0; k < oc; ++k) {
                float4 f = ovf[k];
                if (__float_as_int(f.x) == n) {
                    uint4 u2 = *(const uint4*)(xs + ((size_t)__float_as_int(f.y) << 5));
                    acc8(u2, f.z, s);
                }
            }
        }

        // Combine the two halves: lane l <-> l^32 (same node, same channels).
#pragma unroll
        for (int c = 0; c < 8; ++c) s[c] += __shfl_xor(s[c], 32);

        if (valid && lane < 32) {
            uint4 o;
            o.x = (unsigned int)f2bf(s[0] * inv) | ((unsigned int)f2bf(s[1] * inv) << 16);
            o.y = (unsigned int)f2bf(s[2] * inv) | ((unsigned int)f2bf(s[3] * inv) << 16);
            o.z = (unsigned int)f2bf(s[4] * inv) | ((unsigned int)f2bf(s[5] * inv) << 16);
            o.w = (unsigned int)f2bf(s[6] * inv) | ((unsigned int)f2bf(s[7] * inv) << 16);
            *(uint4*)(&s_agg[ni * 136 + pass * 32 + l4 * 8]) = o;
        }
    }

    // ---- gemm X A-frag prefetch (independent of agg; issues before barrier).
    int l16 = lane & 15;
    int quad = lane >> 4;
    int rb = wave & 1;            // row band (16 rows)
    int ch = wave >> 1;           // col half (64 cols)
    int rowA = min(base + rb * 16 + l16, M - 1);
    const unsigned short* xb0 = x + ((size_t)rowA << 5) + quad * 8;
    bf16x8 af[8];
#pragma unroll
    for (int kc = 0; kc < 4; ++kc) af[kc] = *(const bf16x8*)(xb0 + (((size_t)kc * M) << 5));

    __syncthreads();

    // ---- gemm: out[32,128] = relu([X | s_agg] @ W + b), MFMA 16x16x32.
    // Wave (rb, ch): rows [rb*16, rb*16+16) x cols [ch*64, ch*64+64).
    int lrow = rb * 16 + l16;
#pragma unroll
    for (int kc = 0; kc < 4; ++kc)
        af[kc + 4] = *(const bf16x8*)(&s_agg[lrow * 136 + kc * 32 + quad * 8]);

    floatx4 acc[4];
#pragma unroll
    for (int ci = 0; ci < 4; ++ci) acc[ci] = (floatx4){0.f, 0.f, 0.f, 0.f};

#pragma unroll
    for (int kc = 0; kc < 8; ++kc)
#pragma unroll
        for (int ci = 0; ci < 4; ++ci) {
            int c = ch * 4 + ci;
            bf16x8 bfr = *(const bf16x8*)(Wsw + (((size_t)(c * 8 + kc) * 64 + lane) << 3));
            acc[ci] = __builtin_amdgcn_mfma_f32_16x16x32_bf16(af[kc], bfr, acc[ci], 0, 0, 0);
        }

    int orow0 = base + rb * 16 + quad * 4;
#pragma unroll
    for (int ci = 0; ci < 4; ++ci) {
        int col = (ch * 4 + ci) * 16 + l16;
        float bv = bias[col];
#pragma unroll
        for (int r = 0; r < 4; ++r) {
            int orow = orow0 + r;
            if (orow < M) {
                float v = fmaxf(acc[ci][r] + bv, 0.f);
                if (outF) outF[(size_t)orow * 128 + col] = v;
                else outB[(((size_t)(col >> 5) * M + orow) << 5) + (col & 31)] = f2bf(v);
            }
        }
    }
}

extern "C" void kernel_launch(void* const* d_in, const int* in_sizes, int n_in,
                              void* d_out, int out_size, void* d_ws, size_t ws_size,
                              hipStream_t stream) {
    const float* data = (const float*)d_in[0];
    const int* edge = (const int*)d_in[1];
    const float* att = (const float*)d_in[2];
    const float* w1 = (const float*)d_in[3];
    const float* b1 = (const float*)d_in[4];
    const float* w2 = (const float*)d_in[5];
    const float* b2 = (const float*)d_in[6];

    const int N = in_sizes[0] / HDIM;
    const int E = in_sizes[1] / 2;

    char* ws = (char*)d_ws;
    size_t o = 0;
    auto carve = [&](size_t bytes) -> char* {
        char* r = ws + o;
        o = (o + bytes + 255) & ~(size_t)255;
        return r;
    };
    int* cursor = (int*)carve((size_t)(N + 4) * 4);   // cursor[N] + ovf_cnt at [N]
    int* ovf_cnt = cursor + N;
    unsigned int* pse = (unsigned int*)carve((size_t)N * CAP * 4);  // 4B records
    float4* ovf = (float4*)carve((size_t)E * 16);             // overflow (usually empty)
    unsigned short* data_bf = (unsigned short*)carve((size_t)N * 128 * 2);
    unsigned short* w1s = (unsigned short*)carve(256 * 128 * 2);
    unsigned short* w2s = (unsigned short*)carve(256 * 128 * 2);
    unsigned short* out1_bf = (unsigned short*)carve((size_t)N * 128 * 2);
    float* outF = (float*)d_out;

    // Zero cursor+ovf counters (stream-ordered, graph-capture-safe).
    hipMemsetAsync(cursor, 0, (size_t)(N + 4) * 4, stream);

    int rsize = (N + 7) / 8;
    int nch = (E + FCH - 1) / FCH;
    int nfb = nch * 8;
    int n4 = N * 32;
    int cb = (n4 + 255) / 256;
    k_fill<<<nfb + cb + 256, 256, 0, stream>>>(edge, E, att, cursor, ovf_cnt, pse, ovf,
                                               rsize, nfb, data, data_bf, n4, cb, N,
                                               w1, w1s, w2, w2s);

    int nbk = (N + NPB - 1) / NPB;
    // Layer 1: agg+gemm fused (agg tile via LDS), bf16 slice-major out.
    k_layer<<<nbk, 256, 0, stream>>>(data_bf, pse, cursor, ovf_cnt, ovf,
                                     w1s, b1, nullptr, out1_bf, N);
    // Layer 2: agg+gemm fused, f32 row-major out.
    k_layer<<<nbk, 256, 0, stream>>>(out1_bf, pse, cursor, ovf_cnt, ovf,
                                     w2s, b2, outF, nullptr, N);
}

// Round 12
// 193.068 us; speedup vs baseline: 1.0772x; 1.0772x over previous
//
#include <hip/hip_runtime.h>

// GNN: 2 x (SimpleConv(mean, cat) -> Linear(256->128) -> ReLU)
// N=50000 nodes, E=640000 edges, H=128.
//
// R1-R14: CSR pipeline, bf16, MFMA gemm, 5 kernels + memset. 209.7us.
// R15-R18: slice-major hidden state; quad-per-node gather; fill XCD
//      partition + upfront scan loads. 214.2.
// R19 ACCOUNTING: ~77us dispatch gaps. R20 FAILED (coop launch vs capture).
// R21 REGRESSED 594 (persistent grid pinned occupancy).
// R22: agg+gemm fused per 64-node block. 206.1. k_layer 45us.
// R23 REGRESSED 225 (all-slices-concurrent thrashed L2).
// R24 FAILED correctness (gemm col-split coverage hole). R25 fixed: 205.1.
// R26: NPB=32, occupancy 28->44%, 4x exposure concurrency: k_layer STILL
//      45.1us (FETCH 63->79->97MB across R22/25/26, time constant).
//      INVARIANT IDENTIFIED: 2.56M random gather requests/layer = ~220M
//      req/s/CU = the per-CU outstanding-miss (MSHR ~32 @ ~400cy) ceiling.
//      Occupancy/pipelining can't help; only REQUEST COUNT can.
// R27: slice-PAIR layout [2][N][64] bf16 (128B line-aligned rows). Gather
//      unit = octet (8 lanes x 16B = one full 128B line): 2 requests/edge
//      instead of 4, 100% line utilization. Agg = 2 serial pair-passes
//      (footprint 6.4MB). Cast/gemm-A/out1 adapted; gemm tiling + fill
//      unchanged from R26.

#define HDIM 128
#define CAP 32            // padded CSR slots/node; P(deg>32 | Poisson 12.8) ~ 2e-6
#define FCH 2048          // edges per fill chunk
#define NPB 32            // nodes per k_layer block

typedef __bf16 bf16x8 __attribute__((ext_vector_type(8)));
typedef float floatx4 __attribute__((ext_vector_type(4)));

__device__ __forceinline__ unsigned short f2bf(float f) {
    unsigned int u = __float_as_uint(f);
    unsigned int r = (u + 0x7fff + ((u >> 16) & 1)) >> 16;   // RNE
    return (unsigned short)r;
}
__device__ __forceinline__ float bf2f(unsigned short b) {
    return __uint_as_float((unsigned int)b << 16);
}
__device__ __forceinline__ void acc8(const uint4& u, float a, float* s) {
    s[0] = fmaf(bf2f((unsigned short)(u.x & 0xffff)), a, s[0]);
    s[1] = fmaf(bf2f((unsigned short)(u.x >> 16)), a, s[1]);
    s[2] = fmaf(bf2f((unsigned short)(u.y & 0xffff)), a, s[2]);
    s[3] = fmaf(bf2f((unsigned short)(u.y >> 16)), a, s[3]);
    s[4] = fmaf(bf2f((unsigned short)(u.z & 0xffff)), a, s[4]);
    s[5] = fmaf(bf2f((unsigned short)(u.z >> 16)), a, s[5]);
    s[6] = fmaf(bf2f((unsigned short)(u.w & 0xffff)), a, s[6]);
    s[7] = fmaf(bf2f((unsigned short)(u.w >> 16)), a, s[7]);
}

// Fused: XCD-partitioned padded-CSR fill | fp32->bf16 cast (pair-major
// [2][N][64]) | prepW (wave-coalesced Wsw). Fill: stage-flattened issue.
__global__ __launch_bounds__(256) void k_fill(const int* __restrict__ edge, int E,
                                              const float* __restrict__ att,
                                              int* __restrict__ cursor,
                                              int* __restrict__ ovf_cnt,
                                              unsigned int* __restrict__ pse,
                                              float4* __restrict__ ovf, int rsize,
                                              int nfb,
                                              const float* __restrict__ data,
                                              unsigned short* __restrict__ data_bf, int n4,
                                              int cb, int NN,
                                              const float* __restrict__ w1,
                                              unsigned short* __restrict__ w1s,
                                              const float* __restrict__ w2,
                                              unsigned short* __restrict__ w2s) {
    int b = blockIdx.x;
    int t = threadIdx.x;
    if (b < nfb) {
        __shared__ int s_or;
        if (t == 0) s_or = 0;
        __syncthreads();
        int nw = 2 * E < 512 ? 2 * E : 512;
        int iw = t * 2 + 1;
        int vw = (iw < nw) ? edge[iw] : 0;
        if (vw != 0) atomicOr(&s_or, 1);
        __syncthreads();
        int sh = (s_or == 0) ? 1 : 0;  // 1 => int64 stride, 0 => int32

        int r = b & 7;
        int c = b >> 3;
        int lo = r * rsize;
        int hi = lo + rsize;
        int e0 = c * FCH;
        // Stage 1: 8 dst scan loads (independent).
        int ds[8];
#pragma unroll
        for (int k = 0; k < 8; ++k) {
            int e = e0 + t + k * 256;
            ds[k] = (e < E) ? edge[(size_t)(E + e) << sh] : -1;
        }
        bool ir[8];
#pragma unroll
        for (int k = 0; k < 8; ++k) ir[k] = (ds[k] >= lo && ds[k] < hi);
        // Stage 2: predicated src+att loads (independent).
        int sv[8];
        float av[8];
#pragma unroll
        for (int k = 0; k < 8; ++k) {
            if (ir[k]) {
                int e = e0 + t + k * 256;
                sv[k] = edge[(size_t)e << sh];
                av[k] = att[e];
            }
        }
        // Stage 3: predicated slot atomics (independent).
        int sl[8];
#pragma unroll
        for (int k = 0; k < 8; ++k) {
            if (ir[k]) sl[k] = atomicAdd(&cursor[ds[k]], 1);
        }
        // Stage 4: predicated record stores.
#pragma unroll
        for (int k = 0; k < 8; ++k) {
            if (ir[k]) {
                if (sl[k] < CAP) {
                    unsigned int rec = ((unsigned int)f2bf(av[k]) << 16) | (unsigned int)(sv[k] & 0xffff);
                    pse[(size_t)ds[k] * CAP + sl[k]] = rec;
                } else {
                    int oi = atomicAdd(ovf_cnt, 1);
                    ovf[oi] = make_float4(__int_as_float(ds[k]), __int_as_float(sv[k]), av[k], 0.f);
                }
            }
        }
        return;
    }
    b -= nfb;
    if (b < cb) {
        int i = b * 256 + t;
        if (i < n4) {
            float4 v = ((const float4*)data)[i];
            ushort4 o;
            o.x = f2bf(v.x); o.y = f2bf(v.y); o.z = f2bf(v.z); o.w = f2bf(v.w);
            int nn = i >> 5;           // node
            int c4 = i & 31;           // which float4 of the row (ch 4*c4)
            // pair-major [2][N][64]: pair = c4>>4, offset shorts = (c4&15)*4
            *(ushort4*)(data_bf + (((size_t)(c4 >> 4) * NN + nn) << 6) + ((c4 & 15) << 2)) = o;
        }
        return;
    }
    b -= cb;
    {
        const float* w = (b < 128) ? w1 : w2;
        unsigned short* wt = (b < 128) ? w1s : w2s;
        int bb = (b < 128) ? b : b - 128;
        int idx = bb * 256 + t;          // 0..32767
        int k = idx >> 7;                // 0..255
        int n = idx & 127;               // 0..127
        // wave-coalesced: gemm reads Wsw[((c*8+kc)*64+lane)*8+j]  (R21-validated)
        int c = n >> 4, l16 = n & 15;
        int kc = k >> 5, quad = (k >> 3) & 3, j = k & 7;
        int lane = quad * 16 + l16;
        size_t f = (((size_t)(c * 8 + kc) * 64 + lane) << 3) + j;
        wt[f] = f2bf(w[(size_t)k * 128 + n]);
    }
}

// Fused layer, NPB=32, pair-major x [2][M][64]. Agg: OCTET (8 lanes x 16B =
// one 128B line) per node; 2 serial pair-passes; batches of 8 full-line
// gathers in flight; no cross-lane combine (octet owns distinct channels).
// Gemm: wave = (row band rb=w&1) x (col half ch=w>>1), 4 B-frags from Wsw
// (L2). X A-frags prefetch before the barrier.
// outB (layer1) pair-major bf16; outF (layer2) row-major f32.
__global__ __launch_bounds__(256, 6) void k_layer(const unsigned short* __restrict__ x,
                                                  const unsigned int* __restrict__ pse,
                                                  const int* __restrict__ cursor,
                                                  const int* __restrict__ ovf_cnt,
                                                  const float4* __restrict__ ovf,
                                                  const unsigned short* __restrict__ Wsw,
                                                  const float* __restrict__ bias,
                                                  float* __restrict__ outF,
                                                  unsigned short* __restrict__ outB,
                                                  int M) {
    __shared__ __align__(16) unsigned int s_rec[NPB * 36];      // 4608 B
    __shared__ __align__(16) unsigned short s_agg[NPB * 136];   // 8704 B
    int tid = threadIdx.x;
    int base = blockIdx.x * NPB;

    // Stage 32 nodes x 32 records (256 uint4s, one per thread, coalesced).
    {
        int i = tid >> 3;                // node local 0..31
        int j0 = (tid & 7) << 2;         // slot 0,4,...,28
        int nn = base + i;
        uint4 v = make_uint4(0u, 0u, 0u, 0u);
        if (nn < M) v = *(const uint4*)(pse + ((size_t)nn << 5) + j0);
        *(uint4*)(&s_rec[i * 36 + j0]) = v;
    }
    __syncthreads();

    int lane = tid & 63;
    int wave = tid >> 6;
    int oct = lane >> 3;          // octet 0..7 -> node within wave
    int ol = lane & 7;            // 16B sub-segment of the 128B pair row
    int ni = wave * 8 + oct;      // node local 0..31
    int n = base + ni;
    bool valid = n < M;
    int deg = valid ? cursor[n] : 0;
    int m = min(deg, CAP);
    const unsigned int* rp = &s_rec[ni * 36];
    float inv = 1.0f / fmaxf((float)deg, 1.0f);
    int oc = ovf_cnt[0];

    // ---- agg: 2 serial pair-passes; octet gathers full 128B rows.
#pragma unroll
    for (int pass = 0; pass < 2; ++pass) {
        const unsigned short* xs = x + (((size_t)pass * M) << 6) + (ol << 3);
        float s[8] = {0.f, 0.f, 0.f, 0.f, 0.f, 0.f, 0.f, 0.f};

        for (int j = 0; j < m; j += 8) {       // 8 full-line gathers in flight
            unsigned int rr[8];
#pragma unroll
            for (int k = 0; k < 8; ++k) {
                unsigned int rv = rp[j + k];         // padded row (36), j+k<=31
                rr[k] = (j + k < m) ? rv : 0u;       // rec=0 -> row0, att=0
            }
            uint4 uu[8];
#pragma unroll
            for (int k = 0; k < 8; ++k)
                uu[k] = *(const uint4*)(xs + ((size_t)(rr[k] & 0xffffu) << 6));
#pragma unroll
            for (int k = 0; k < 8; ++k)
                acc8(uu[k], __uint_as_float(rr[k] & 0xffff0000u), s);
        }

        if (oc > 0 && valid) {     // overflow path (normally skipped)
            for (int k = 0; k < oc; ++k) {
                float4 f = ovf[k];
                if (__float_as_int(f.x) == n) {
                    uint4 u2 = *(const uint4*)(xs + ((size_t)__float_as_int(f.y) << 6));
                    acc8(u2, f.z, s);
                }
            }
        }

        // Write 8 ch (16B) of the pair row to the block-local agg tile.
        uint4 o;
        o.x = (unsigned int)f2bf(s[0] * inv) | ((unsigned int)f2bf(s[1] * inv) << 16);
        o.y = (unsigned int)f2bf(s[2] * inv) | ((unsigned int)f2bf(s[3] * inv) << 16);
        o.z = (unsigned int)f2bf(s[4] * inv) | ((unsigned int)f2bf(s[5] * inv) << 16);
        o.w = (unsigned int)f2bf(s[6] * inv) | ((unsigned int)f2bf(s[7] * inv) << 16);
        *(uint4*)(&s_agg[ni * 136 + pass * 64 + ol * 8]) = o;
    }

    // ---- gemm X A-frag prefetch (independent of agg; issues before barrier).
    int l16 = lane & 15;
    int quad = lane >> 4;
    int rb = wave & 1;            // row band (16 rows)
    int ch = wave >> 1;           // col half (64 cols)
    int rowA = min(base + rb * 16 + l16, M - 1);
    bf16x8 af[8];
#pragma unroll
    for (int kc = 0; kc < 4; ++kc)      // ch [kc*32, kc*32+32): pair kc>>1
        af[kc] = *(const bf16x8*)(x + (((size_t)(kc >> 1) * M + rowA) << 6)
                                    + (kc & 1) * 32 + quad * 8);

    __syncthreads();

    // ---- gemm: out[32,128] = relu([X | s_agg] @ W + b), MFMA 16x16x32.
    // Wave (rb, ch): rows [rb*16, rb*16+16) x cols [ch*64, ch*64+64).
    int lrow = rb * 16 + l16;
#pragma unroll
    for (int kc = 0; kc < 4; ++kc)
        af[kc + 4] = *(const bf16x8*)(&s_agg[lrow * 136 + kc * 32 + quad * 8]);

    floatx4 acc[4];
#pragma unroll
    for (int ci = 0; ci < 4; ++ci) acc[ci] = (floatx4){0.f, 0.f, 0.f, 0.f};

#pragma unroll
    for (int kc = 0; kc < 8; ++kc)
#pragma unroll
        for (int ci = 0; ci < 4; ++ci) {
            int c = ch * 4 + ci;
            bf16x8 bfr = *(const bf16x8*)(Wsw + (((size_t)(c * 8 + kc) * 64 + lane) << 3));
            acc[ci] = __builtin_amdgcn_mfma_f32_16x16x32_bf16(af[kc], bfr, acc[ci], 0, 0, 0);
        }

    int orow0 = base + rb * 16 + quad * 4;
#pragma unroll
    for (int ci = 0; ci < 4; ++ci) {
        int col = (ch * 4 + ci) * 16 + l16;
        float bv = bias[col];
#pragma unroll
        for (int r = 0; r < 4; ++r) {
            int orow = orow0 + r;
            if (orow < M) {
                float v = fmaxf(acc[ci][r] + bv, 0.f);
                if (outF) outF[(size_t)orow * 128 + col] = v;
                else outB[(((size_t)(col >> 6) * M + orow) << 6) + (col & 63)] = f2bf(v);
            }
        }
    }
}

extern "C" void kernel_launch(void* const* d_in, const int* in_sizes, int n_in,
                              void* d_out, int out_size, void* d_ws, size_t ws_size,
                              hipStream_t stream) {
    const float* data = (const float*)d_in[0];
    const int* edge = (const int*)d_in[1];
    const float* att = (const float*)d_in[2];
    const float* w1 = (const float*)d_in[3];
    const float* b1 = (const float*)d_in[4];
    const float* w2 = (const float*)d_in[5];
    const float* b2 = (const float*)d_in[6];

    const int N = in_sizes[0] / HDIM;
    const int E = in_sizes[1] / 2;

    char* ws = (char*)d_ws;
    size_t o = 0;
    auto carve = [&](size_t bytes) -> char* {
        char* r = ws + o;
        o = (o + bytes + 255) & ~(size_t)255;
        return r;
    };
    int* cursor = (int*)carve((size_t)(N + 4) * 4);   // cursor[N] + ovf_cnt at [N]
    int* ovf_cnt = cursor + N;
    unsigned int* pse = (unsigned int*)carve((size_t)N * CAP * 4);  // 4B records
    float4* ovf = (float4*)carve((size_t)E * 16);             // overflow (usually empty)
    unsigned short* data_bf = (unsigned short*)carve((size_t)N * 128 * 2);
    unsigned short* w1s = (unsigned short*)carve(256 * 128 * 2);
    unsigned short* w2s = (unsigned short*)carve(256 * 128 * 2);
    unsigned short* out1_bf = (unsigned short*)carve((size_t)N * 128 * 2);
    float* outF = (float*)d_out;

    // Zero cursor+ovf counters (stream-ordered, graph-capture-safe).
    hipMemsetAsync(cursor, 0, (size_t)(N + 4) * 4, stream);

    int rsize = (N + 7) / 8;
    int nch = (E + FCH - 1) / FCH;
    int nfb = nch * 8;
    int n4 = N * 32;
    int cb = (n4 + 255) / 256;
    k_fill<<<nfb + cb + 256, 256, 0, stream>>>(edge, E, att, cursor, ovf_cnt, pse, ovf,
                                               rsize, nfb, data, data_bf, n4, cb, N,
                                               w1, w1s, w2, w2s);

    int nbk = (N + NPB - 1) / NPB;
    // Layer 1: agg+gemm fused (agg tile via LDS), bf16 pair-major out.
    k_layer<<<nbk, 256, 0, stream>>>(data_bf, pse, cursor, ovf_cnt, ovf,
                                     w1s, b1, nullptr, out1_bf, N);
    // Layer 2: agg+gemm fused, f32 row-major out.
    k_layer<<<nbk, 256, 0, stream>>>(out1_bf, pse, cursor, ovf_cnt, ovf,
                                     w2s, b2, outF, nullptr, N);
}